// Round 2
// baseline (1158.175 us; speedup 1.0000x reference)
//
#include <hip/hip_runtime.h>
#include <math.h>

#define BB 8
#define CC 128
#define NN 2048
#define KK 10
#define TWO_CC 256

// exact-ranking comparator (f64): larger key wins; ties -> smaller index (JAX semantics)
__device__ __forceinline__ void insert10(double (&LV)[10], int (&LI)[10], double v, int m) {
    if (v > LV[9] || (v == LV[9] && m < LI[9])) {
        LV[9] = v; LI[9] = m;
#pragma unroll
        for (int q = 9; q >= 1; --q) {
            bool sw = (LV[q] > LV[q - 1]) || (LV[q] == LV[q - 1] && LI[q] < LI[q - 1]);
            double tv = LV[q], tu = LV[q - 1];
            int iv = LI[q], iu = LI[q - 1];
            LV[q]     = sw ? tu : tv;
            LV[q - 1] = sw ? tv : tu;
            LI[q]     = sw ? iu : iv;
            LI[q - 1] = sw ? iv : iu;
        }
    }
}

// f32 screening comparator, 16 deep (margin 6 over the true top-10)
__device__ __forceinline__ void insert16f(float (&LV)[16], int (&LI)[16], float v, int m) {
    if (v > LV[15] || (v == LV[15] && m < LI[15])) {
        LV[15] = v; LI[15] = m;
#pragma unroll
        for (int q = 15; q >= 1; --q) {
            bool sw = (LV[q] > LV[q - 1]) || (LV[q] == LV[q - 1] && LI[q] < LI[q - 1]);
            float tv = LV[q], tu = LV[q - 1];
            int iv = LI[q], iu = LI[q - 1];
            LV[q]     = sw ? tu : tv;
            LV[q - 1] = sw ? tv : tu;
            LI[q]     = sw ? iu : iv;
            LI[q - 1] = sw ? iv : iu;
        }
    }
}

// ---------------- squared column norms in f64 ----------------
__global__ __launch_bounds__(256) void k_xx(const float* __restrict__ h, double* __restrict__ xx) {
    int t = blockIdx.x * 256 + threadIdx.x;
    if (t >= BB * NN) return;
    int b = t / NN, n = t % NN;
    const float* p = h + (size_t)b * CC * NN + n;
    double s = 0.0;
#pragma unroll
    for (int c = 0; c < CC; ++c) {
        double v = (double)p[(size_t)c * NN];
        s += v * v;
    }
    xx[t] = s;
}

// ---------------- f32 distance screen + partial top-16 ----------------
// block: 64 rows (n0..n0+63) of batch b, HALF of the candidate range (my*1024 .. +1023).
// 256 threads; tx=t&7 (8 cols each), ty=t>>3 (2 rows each). Per-thread 2x8 f32 tile.
// Writes 16 candidate indices per (row, half); k_refine re-scores them in f64.
__global__ __launch_bounds__(256, 2) void k_knn(const float* __restrict__ h, const double* __restrict__ xxg,
                                                int* __restrict__ cand) {
    __shared__ __align__(16) char smem[65536];
    float* At2 = (float*)smem;                 // [128][64] fp32, k-major
    float* Bsm = (float*)(smem + 32768);       // [128][64] fp32, k-major
    float* mgV = (float*)smem;                 // merge overlay on At2: [64][4][16] f32
    int*   mgI = (int*)(smem + 16384);         // [64][4][16] int

    int t = threadIdx.x;
    int tx = t & 7, ty = t >> 3;               // ty 0..31 -> rows 2ty, 2ty+1
    int b = blockIdx.z;
    int my = blockIdx.y;
    int n0 = blockIdx.x * 64;
    const float* hb = h + (size_t)b * CC * NN;

    // stage A-tile transposed: At2[c][j] = h[b][c][n0+j]
#pragma unroll
    for (int i = 0; i < 8; ++i) {
        int G = t + 256 * i;            // 0..2047 float4-groups
        int c = G >> 4, u = G & 15;
        float4 v = *(const float4*)(hb + (size_t)c * NN + n0 + u * 4);
        *(float4*)(At2 + c * 64 + u * 4) = v;
    }

    float LV[2][16]; int LI[2][16];
#pragma unroll
    for (int rr = 0; rr < 2; ++rr)
#pragma unroll
        for (int q = 0; q < 16; ++q) { LV[rr][q] = -3.0e38f; LI[rr][q] = 0x7FFFFFFF; }

    for (int mt = 0; mt < 16; ++mt) {
        int m0 = my * 1024 + mt * 64;
        float xs[8];
#pragma unroll
        for (int j = 0; j < 8; ++j) xs[j] = (float)xxg[b * NN + m0 + 8 * tx + j];

        __syncthreads();                 // Bsm free (also covers At2 staging on mt=0)
#pragma unroll
        for (int i = 0; i < 8; ++i) {
            int G = t + 256 * i;        // 0..2047 float4-groups
            int c = G >> 4, u = G & 15;
            float4 v = *(const float4*)(hb + (size_t)c * NN + m0 + u * 4);
            *(float4*)(Bsm + c * 64 + u * 4) = v;
        }
        __syncthreads();

        float acc[2][8] = {};
        const float* pA = At2 + 2 * ty;
        const float* pB = Bsm + 8 * tx;
#pragma unroll 4
        for (int k = 0; k < 128; ++k) {
            float2 af  = *(const float2*)(pA + k * 64);
            float4 bf0 = *(const float4*)(pB + k * 64);
            float4 bf1 = *(const float4*)(pB + k * 64 + 4);
            acc[0][0] += af.x * bf0.x; acc[0][1] += af.x * bf0.y;
            acc[0][2] += af.x * bf0.z; acc[0][3] += af.x * bf0.w;
            acc[0][4] += af.x * bf1.x; acc[0][5] += af.x * bf1.y;
            acc[0][6] += af.x * bf1.z; acc[0][7] += af.x * bf1.w;
            acc[1][0] += af.y * bf0.x; acc[1][1] += af.y * bf0.y;
            acc[1][2] += af.y * bf0.z; acc[1][3] += af.y * bf0.w;
            acc[1][4] += af.y * bf1.x; acc[1][5] += af.y * bf1.y;
            acc[1][6] += af.y * bf1.z; acc[1][7] += af.y * bf1.w;
        }
#pragma unroll
        for (int rr = 0; rr < 2; ++rr)
#pragma unroll
            for (int j = 0; j < 8; ++j) {
                float v = fmaf(2.f, acc[rr][j], -xs[j]);
                insert16f(LV[rr], LI[rr], v, m0 + 8 * tx + j);
            }
    }

    // hierarchical merge across tx: 8 -> 4 -> 2 -> 1 lists per row
    for (int p = 0; p < 3; ++p) {
        int span = 1 << p;
        __syncthreads();
        bool act = (tx & (span - 1)) == 0;
        int g = tx >> p;
        if (act && (g & 1)) {
            int slot = g >> 1;
#pragma unroll
            for (int rr = 0; rr < 2; ++rr) {
                int base = ((2 * ty + rr) * 4 + slot) * 16;
#pragma unroll
                for (int q = 0; q < 16; ++q) { mgV[base + q] = LV[rr][q]; mgI[base + q] = LI[rr][q]; }
            }
        }
        __syncthreads();
        if (act && !(g & 1)) {
            int slot = g >> 1;
#pragma unroll
            for (int rr = 0; rr < 2; ++rr) {
                int base = ((2 * ty + rr) * 4 + slot) * 16;
#pragma unroll
                for (int q = 0; q < 16; ++q) insert16f(LV[rr], LI[rr], mgV[base + q], mgI[base + q]);
            }
        }
    }
    if (tx == 0) {
#pragma unroll
        for (int rr = 0; rr < 2; ++rr) {
            int n = n0 + 2 * ty + rr;
            int* op = cand + (((size_t)(b * 2 + my) * NN + n) << 4);
#pragma unroll
            for (int q = 0; q < 16; ++q) op[q] = LI[rr][q];
        }
    }
}

// ---------------- exact f64 re-score of the 32 surviving candidates per row ----------------
// block: 8 rows x 32 candidates. Reads contiguous rows of ht (b,n,c layout).
__global__ __launch_bounds__(256) void k_refine(const float* __restrict__ ht, const double* __restrict__ xxg,
                                                const int* __restrict__ cand, int* __restrict__ idxout) {
    __shared__ double vv[8][32];
    __shared__ int    ii[8][32];
    int rg = threadIdx.x >> 5;          // row within block
    int cl = threadIdx.x & 31;          // candidate slot
    int r  = blockIdx.x * 8 + rg;
    int b = r >> 11, n = r & (NN - 1);
    int half = cl >> 4, q = cl & 15;
    int m = cand[(((size_t)(b * 2 + half) * NN + n) << 4) + q];
    const float* pn = ht + ((size_t)b * NN + n) * CC;
    const float* pm = ht + ((size_t)b * NN + m) * CC;
    double acc = 0.0;
#pragma unroll
    for (int i = 0; i < 32; ++i) {
        float4 a = *(const float4*)(pn + 4 * i);
        float4 c = *(const float4*)(pm + 4 * i);
        acc += (double)a.x * (double)c.x + (double)a.y * (double)c.y
             + (double)a.z * (double)c.z + (double)a.w * (double)c.w;
    }
    vv[rg][cl] = 2.0 * acc - xxg[b * NN + m];
    ii[rg][cl] = m;
    __syncthreads();
    if (cl == 0) {
        double LV[10]; int LI[10];
#pragma unroll
        for (int j = 0; j < 10; ++j) { LV[j] = -1.0e300; LI[j] = 0x7FFFFFFF; }
        for (int j = 0; j < 32; ++j) insert10(LV, LI, vv[rg][j], ii[rg][j]);
        int* op = idxout + (size_t)r * KK;
#pragma unroll
        for (int j = 0; j < 10; ++j) op[j] = LI[j];
    }
}

// ---------------- transpose: ht[b][n][c] = h[b][c][n] ----------------
__global__ __launch_bounds__(256) void k_tr(const float* __restrict__ h, float* __restrict__ ht) {
    __shared__ float tile[32][33];
    int b = blockIdx.z, c0 = blockIdx.y * 32, n0 = blockIdx.x * 32;
    int tx = threadIdx.x & 31, tyy = threadIdx.x >> 5;
    const float* hb = h + (size_t)b * CC * NN;
#pragma unroll
    for (int i = 0; i < 4; ++i)
        tile[tyy + i * 8][tx] = hb[(size_t)(c0 + tyy + i * 8) * NN + n0 + tx];
    __syncthreads();
    float* htb = ht + (size_t)b * NN * CC;
#pragma unroll
    for (int i = 0; i < 4; ++i)
        htb[(size_t)(n0 + tyy + i * 8) * CC + c0 + tx] = tile[tx][tyy + i * 8];
}

// ---------------- coalesced neighbor mean from ht ----------------
__global__ __launch_bounds__(256) void k_gather(const float* __restrict__ ht, const int* __restrict__ idx,
                                                float* __restrict__ M) {
    int bn = blockIdx.x * 2 + (threadIdx.x >> 7);
    int c = threadIdx.x & 127;
    int b = bn >> 11;
    const int* ip = idx + (size_t)bn * KK;
    const float* hb = ht + (size_t)b * NN * CC;
    float s = 0.f;
#pragma unroll
    for (int k = 0; k < KK; ++k) s += hb[(size_t)ip[k] * CC + c];
    M[(size_t)bn * CC + c] = s * (1.f / KK);
}

// ---------------- y = Wa*M + (Wb-Wa)*h + bias ----------------
__global__ __launch_bounds__(256) void k_gemm(const float* __restrict__ M, const float* __restrict__ h,
                                              const float* __restrict__ W, const float* __restrict__ bias,
                                              float* __restrict__ y) {
    __shared__ float Ws[64][33];
    __shared__ float Xs[32][65];
    int b = blockIdx.z;
    int o0 = blockIdx.y * 64;
    int n0 = blockIdx.x * 64;
    int tid = threadIdx.x;
    int tx = tid & 15, ty = tid >> 4;
    float acc[4][4] = {};
    const float* Mb = M + (size_t)b * NN * CC;
    const float* hb = h + (size_t)b * CC * NN;

    for (int c0 = 0; c0 < CC; c0 += 32) {
        for (int i = tid; i < 64 * 32; i += 256) {
            int c = i & 31, o = i >> 5;
            Ws[o][c] = W[(size_t)(o0 + o) * TWO_CC + c0 + c];
        }
        for (int i = tid; i < 64 * 32; i += 256) {
            int c = i & 31, nn = i >> 5;
            Xs[c][nn] = Mb[(size_t)(n0 + nn) * CC + c0 + c];
        }
        __syncthreads();
        for (int c = 0; c < 32; ++c) {
            float a[4], bb[4];
#pragma unroll
            for (int q = 0; q < 4; ++q) { a[q] = Ws[ty * 4 + q][c]; bb[q] = Xs[c][tx * 4 + q]; }
#pragma unroll
            for (int i2 = 0; i2 < 4; ++i2)
#pragma unroll
                for (int j = 0; j < 4; ++j) acc[i2][j] += a[i2] * bb[j];
        }
        __syncthreads();
    }
    for (int c0 = 0; c0 < CC; c0 += 32) {
        for (int i = tid; i < 64 * 32; i += 256) {
            int c = i & 31, o = i >> 5;
            const float* wr = W + (size_t)(o0 + o) * TWO_CC;
            Ws[o][c] = wr[CC + c0 + c] - wr[c0 + c];
        }
        for (int i = tid; i < 64 * 32; i += 256) {
            int nn = i & 63, c = i >> 6;
            Xs[c][nn] = hb[(size_t)(c0 + c) * NN + n0 + nn];
        }
        __syncthreads();
        for (int c = 0; c < 32; ++c) {
            float a[4], bb[4];
#pragma unroll
            for (int q = 0; q < 4; ++q) { a[q] = Ws[ty * 4 + q][c]; bb[q] = Xs[c][tx * 4 + q]; }
#pragma unroll
            for (int i2 = 0; i2 < 4; ++i2)
#pragma unroll
                for (int j = 0; j < 4; ++j) acc[i2][j] += a[i2] * bb[j];
        }
        __syncthreads();
    }
#pragma unroll
    for (int i2 = 0; i2 < 4; ++i2) {
        int o = o0 + ty * 4 + i2;
        float bv = bias[o];
#pragma unroll
        for (int j = 0; j < 4; ++j)
            y[((size_t)b * CC + o) * NN + n0 + tx * 4 + j] = acc[i2][j] + bv;
    }
}

// ---------------- per-(b,o) mean/var(ddof=1), relu, optional residual ----------------
__global__ __launch_bounds__(256) void k_norm(const float* __restrict__ y, const float* __restrict__ res,
                                              float* __restrict__ out, int add_res) {
    int bo = blockIdx.x;
    const float* row = y + (size_t)bo * NN;
    float s = 0.f, s2 = 0.f;
    for (int n = threadIdx.x; n < NN; n += 256) {
        float v = row[n];
        s += v;
        s2 += v * v;
    }
#pragma unroll
    for (int off = 32; off > 0; off >>= 1) {
        s += __shfl_down(s, off, 64);
        s2 += __shfl_down(s2, off, 64);
    }
    __shared__ float ss[4], ss2[4];
    int wave = threadIdx.x >> 6, lane = threadIdx.x & 63;
    if (lane == 0) { ss[wave] = s; ss2[wave] = s2; }
    __syncthreads();
    if (threadIdx.x == 0) {
        float S = ss[0] + ss[1] + ss[2] + ss[3];
        float S2 = ss2[0] + ss2[1] + ss2[2] + ss2[3];
        float mean = S * (1.f / NN);
        float var = (S2 - S * mean) * (1.f / (NN - 1));
        ss[0] = mean;
        ss2[0] = rsqrtf(var + 1e-3f);
    }
    __syncthreads();
    float mean = ss[0], inv = ss2[0];
    for (int n = threadIdx.x; n < NN; n += 256) {
        float v = (row[n] - mean) * inv;
        v = fmaxf(v, 0.f);
        if (add_res) v += res[(size_t)bo * NN + n];
        out[(size_t)bo * NN + n] = v;
    }
}

extern "C" void kernel_launch(void* const* d_in, const int* in_sizes, int n_in,
                              void* d_out, int out_size, void* d_ws, size_t ws_size,
                              hipStream_t stream) {
    const float* x  = (const float*)d_in[0];
    const float* W1 = (const float*)d_in[1];
    const float* b1 = (const float*)d_in[2];
    const float* W2 = (const float*)d_in[3];
    const float* b2 = (const float*)d_in[4];
    float* out = (float*)d_out;

    char* wsb = (char*)d_ws;
    double* xx = (double*)wsb;                          // 8*2048 f64          = 131072 B
    char* p = wsb + (size_t)BB * NN * 8;
    int* idx = (int*)p;       p += (size_t)BB * NN * KK * 4;    // 655360 B
    float* ht = (float*)p;    p += (size_t)BB * NN * CC * 4;    // 8 MB
    float* M  = (float*)p;    p += (size_t)BB * NN * CC * 4;    // 8 MB
    float* y  = (float*)p;    p += (size_t)BB * CC * NN * 4;    // 8 MB
    float* h1 = (float*)p;                                      // 8 MB

    // screened candidate lists (16 per row per m-half) live in y's region — y is dead during KNN.
    int* cand = (int*)y;                                        // 8*2*2048*16*4 = 2 MB

    auto layer = [&](const float* hin, const float* Wt, const float* bt, float* hout, int add_res) {
        hipLaunchKernelGGL(k_xx, dim3((BB * NN) / 256), dim3(256), 0, stream, hin, xx);
        hipLaunchKernelGGL(k_tr, dim3(NN / 32, CC / 32, BB), dim3(256), 0, stream, hin, ht);
        hipLaunchKernelGGL(k_knn, dim3(NN / 64, 2, BB), dim3(256), 0, stream, hin, xx, cand);
        hipLaunchKernelGGL(k_refine, dim3((BB * NN) / 8), dim3(256), 0, stream, ht, xx, cand, idx);
        hipLaunchKernelGGL(k_gather, dim3(BB * NN / 2), dim3(256), 0, stream, ht, idx, M);
        hipLaunchKernelGGL(k_gemm, dim3(NN / 64, CC / 64, BB), dim3(256), 0, stream, M, hin, Wt, bt, y);
        hipLaunchKernelGGL(k_norm, dim3(BB * CC), dim3(256), 0, stream, y, x, hout, add_res);
    };

    layer(x, W1, b1, h1, 0);
    layer(h1, W2, b2, out, 1);
}

// Round 3
// 1036.390 us; speedup vs baseline: 1.1175x; 1.1175x over previous
//
#include <hip/hip_runtime.h>
#include <math.h>

#define BB 8
#define CC 128
#define NN 2048
#define KK 10
#define TWO_CC 256
#define DEPTH 12
#define MYS 4            // candidate-range splits per row

// f32 screening comparator, DEPTH deep (margin 2 over exact-sufficient 10)
__device__ __forceinline__ void insert12f(float (&LV)[DEPTH], int (&LI)[DEPTH], float v, int m) {
    if (v > LV[DEPTH - 1] || (v == LV[DEPTH - 1] && m < LI[DEPTH - 1])) {
        LV[DEPTH - 1] = v; LI[DEPTH - 1] = m;
#pragma unroll
        for (int q = DEPTH - 1; q >= 1; --q) {
            bool sw = (LV[q] > LV[q - 1]) || (LV[q] == LV[q - 1] && LI[q] < LI[q - 1]);
            float tv = LV[q], tu = LV[q - 1];
            int iv = LI[q], iu = LI[q - 1];
            LV[q]     = sw ? tu : tv;
            LV[q - 1] = sw ? tv : tu;
            LI[q]     = sw ? iu : iv;
            LI[q - 1] = sw ? iv : iu;
        }
    }
}

// async global->LDS, 16B per lane; lds dest = wave-uniform base + lane*16
__device__ __forceinline__ void gload16(const float* g, float* l) {
    __builtin_amdgcn_global_load_lds((const __attribute__((address_space(1))) void*)g,
                                     (__attribute__((address_space(3))) void*)l, 16, 0, 0);
}

// ---------------- squared column norms in f64 ----------------
__global__ __launch_bounds__(256) void k_xx(const float* __restrict__ h, double* __restrict__ xx) {
    int t = blockIdx.x * 256 + threadIdx.x;
    if (t >= BB * NN) return;
    int b = t / NN, n = t % NN;
    const float* p = h + (size_t)b * CC * NN + n;
    double s = 0.0;
#pragma unroll
    for (int c = 0; c < CC; ++c) {
        double v = (double)p[(size_t)c * NN];
        s += v * v;
    }
    xx[t] = s;
}

// ---------------- f32 distance screen + partial top-12 ----------------
// block: 64 rows (n0..n0+63) of batch b, QUARTER of the candidate range (my*512 .. +511).
// 256 threads; tx=t&7 (8 cols), ty=t>>3 (2 rows). Per-thread 2x8 f32 tile.
// A-tile [128ch][64rows] resident (staged once, global_load_lds); B staged in 32-ch
// quarters [32][64]. LDS = 32KB+8KB = 40KB -> 4 blocks/CU; grid 1024 = exact fill.
__global__ __launch_bounds__(256, 4) void k_knn(const float* __restrict__ h, const double* __restrict__ xxg,
                                                int* __restrict__ cand) {
    __shared__ __align__(16) float At[128 * 64];   // 32KB, k-major: At[k][j]
    __shared__ __align__(16) float Bq[32 * 64];    // 8KB,  Bq[kk][u]
    float* mgV = At;                               // merge overlay: [64][4][12] f32
    int*   mgI = (int*)(At + 64 * 4 * DEPTH);      // [64][4][12] int (within At's 32KB)

    int t = threadIdx.x;
    int tx = t & 7, ty = t >> 3;                   // ty 0..31 -> rows 2ty, 2ty+1
    int w = t >> 6, lane = t & 63;
    int b = blockIdx.z;
    int my = blockIdx.y;
    int n0 = blockIdx.x * 64;
    const float* hb = h + (size_t)b * CC * NN;

    // stage full A-tile once: 2048 float4-slots, 8 calls/wave
#pragma unroll
    for (int i = 0; i < 8; ++i) {
        int sb = (i * 4 + w) * 64;                 // wave-uniform slot base
        int g = sb + lane;
        gload16(hb + (size_t)(g >> 4) * NN + n0 + ((g & 15) << 2), At + 4 * sb);
    }

    float LV[2][DEPTH]; int LI[2][DEPTH];
#pragma unroll
    for (int rr = 0; rr < 2; ++rr)
#pragma unroll
        for (int q = 0; q < DEPTH; ++q) { LV[rr][q] = -3.0e38f; LI[rr][q] = 0x7FFFFFFF; }

    for (int mt = 0; mt < 8; ++mt) {
        int m0 = my * 512 + mt * 64;
        float xs[8];
#pragma unroll
        for (int j = 0; j < 8; ++j) xs[j] = (float)xxg[b * NN + m0 + 8 * tx + j];

        float acc[2][8] = {};
        for (int ch = 0; ch < 4; ++ch) {           // 32-channel chunks
            int c0 = ch * 32;
            __syncthreads();                       // Bq free (also covers A staging on first pass)
#pragma unroll
            for (int i = 0; i < 2; ++i) {          // 512 slots, 2 calls/wave
                int sb = (i * 4 + w) * 64;
                int g = sb + lane;
                gload16(hb + (size_t)(c0 + (g >> 4)) * NN + m0 + ((g & 15) << 2), Bq + 4 * sb);
            }
            __syncthreads();

            const float* pA = At + c0 * 64 + 2 * ty;
            const float* pB = Bq + 8 * tx;
#pragma unroll 4
            for (int kk = 0; kk < 32; ++kk) {
                float2 af  = *(const float2*)(pA + kk * 64);
                float4 bf0 = *(const float4*)(pB + kk * 64);
                float4 bf1 = *(const float4*)(pB + kk * 64 + 4);
                acc[0][0] += af.x * bf0.x; acc[0][1] += af.x * bf0.y;
                acc[0][2] += af.x * bf0.z; acc[0][3] += af.x * bf0.w;
                acc[0][4] += af.x * bf1.x; acc[0][5] += af.x * bf1.y;
                acc[0][6] += af.x * bf1.z; acc[0][7] += af.x * bf1.w;
                acc[1][0] += af.y * bf0.x; acc[1][1] += af.y * bf0.y;
                acc[1][2] += af.y * bf0.z; acc[1][3] += af.y * bf0.w;
                acc[1][4] += af.y * bf1.x; acc[1][5] += af.y * bf1.y;
                acc[1][6] += af.y * bf1.z; acc[1][7] += af.y * bf1.w;
            }
        }
#pragma unroll
        for (int rr = 0; rr < 2; ++rr)
#pragma unroll
            for (int j = 0; j < 8; ++j) {
                float v = fmaf(2.f, acc[rr][j], -xs[j]);
                insert12f(LV[rr], LI[rr], v, m0 + 8 * tx + j);
            }
    }

    // hierarchical merge across tx: 8 -> 4 -> 2 -> 1 lists per row
    for (int p = 0; p < 3; ++p) {
        int span = 1 << p;
        __syncthreads();
        bool act = (tx & (span - 1)) == 0;
        int g = tx >> p;
        if (act && (g & 1)) {
            int slot = g >> 1;
#pragma unroll
            for (int rr = 0; rr < 2; ++rr) {
                int base = ((2 * ty + rr) * 4 + slot) * DEPTH;
#pragma unroll
                for (int q = 0; q < DEPTH; ++q) { mgV[base + q] = LV[rr][q]; mgI[base + q] = LI[rr][q]; }
            }
        }
        __syncthreads();
        if (act && !(g & 1)) {
            int slot = g >> 1;
#pragma unroll
            for (int rr = 0; rr < 2; ++rr) {
                int base = ((2 * ty + rr) * 4 + slot) * DEPTH;
#pragma unroll
                for (int q = 0; q < DEPTH; ++q) insert12f(LV[rr], LI[rr], mgV[base + q], mgI[base + q]);
            }
        }
    }
    if (tx == 0) {
#pragma unroll
        for (int rr = 0; rr < 2; ++rr) {
            int n = n0 + 2 * ty + rr;
            int* op = cand + (((size_t)(b * MYS + my) * NN + n) * DEPTH);
#pragma unroll
            for (int q = 0; q < DEPTH; ++q) op[q] = LI[rr][q];
        }
    }
}

// ---------------- fused: exact f64 re-score of 48 candidates + top-10 + neighbor mean ----
// one wave per row; coalesced float2 loads from ht; butterfly f64 reduce;
// exact (v desc, idx asc) extraction; mean in rank order (same f32 order as before).
__global__ __launch_bounds__(64) void k_rg(const float* __restrict__ ht, const double* __restrict__ xxg,
                                           const int* __restrict__ cand, float* __restrict__ M) {
    int r = blockIdx.x;                      // 0..BB*NN-1
    int b = r >> 11, n = r & (NN - 1);
    int lane = threadIdx.x;
    const float* base = ht + (size_t)b * NN * CC;
    float2 xn = *(const float2*)(base + (size_t)n * CC + 2 * lane);

    int myc = 0; double myxx = 0.0;
    if (lane < MYS * DEPTH) {
        int my = lane / DEPTH, q = lane - DEPTH * my;
        myc = cand[((size_t)(b * MYS + my) * NN + n) * DEPTH + q];
        myxx = xxg[b * NN + myc];
    }
    double sv = -1.0e300;
    int si = (lane < MYS * DEPTH) ? myc : (0x40000000 + lane);   // unique sentinels

    for (int c = 0; c < MYS * DEPTH; ++c) {
        int m = __shfl(myc, c, 64);
        float2 pm = *(const float2*)(base + (size_t)m * CC + 2 * lane);
        double d = (double)xn.x * (double)pm.x + (double)xn.y * (double)pm.y;
#pragma unroll
        for (int off = 1; off < 64; off <<= 1) d += __shfl_xor(d, off, 64);
        double xxm = __shfl(myxx, c, 64);
        double sc = 2.0 * d - xxm;
        if (lane == c) sv = sc;
    }

    int rank[10];
#pragma unroll
    for (int rr = 0; rr < 10; ++rr) {
        double bv = sv; int bi = si;
#pragma unroll
        for (int off = 32; off; off >>= 1) {
            double ov = __shfl_xor(bv, off, 64);
            int oi = __shfl_xor(bi, off, 64);
            bool tk = (ov > bv) || (ov == bv && oi < bi);
            bv = tk ? ov : bv; bi = tk ? oi : bi;
        }
        rank[rr] = bi;                       // wave-uniform
        if (si == bi) sv = -1.0e301;         // knock out winner
    }

    float sx = 0.f, sy = 0.f;
#pragma unroll
    for (int rr = 0; rr < 10; ++rr) {
        float2 pm = *(const float2*)(base + (size_t)rank[rr] * CC + 2 * lane);
        sx += pm.x; sy += pm.y;
    }
    float2 o; o.x = sx * (1.f / KK); o.y = sy * (1.f / KK);
    *(float2*)(M + (size_t)r * CC + 2 * lane) = o;
}

// ---------------- transpose: ht[b][n][c] = h[b][c][n] ----------------
__global__ __launch_bounds__(256) void k_tr(const float* __restrict__ h, float* __restrict__ ht) {
    __shared__ float tile[32][33];
    int b = blockIdx.z, c0 = blockIdx.y * 32, n0 = blockIdx.x * 32;
    int tx = threadIdx.x & 31, tyy = threadIdx.x >> 5;
    const float* hb = h + (size_t)b * CC * NN;
#pragma unroll
    for (int i = 0; i < 4; ++i)
        tile[tyy + i * 8][tx] = hb[(size_t)(c0 + tyy + i * 8) * NN + n0 + tx];
    __syncthreads();
    float* htb = ht + (size_t)b * NN * CC;
#pragma unroll
    for (int i = 0; i < 4; ++i)
        htb[(size_t)(n0 + tyy + i * 8) * CC + c0 + tx] = tile[tx][tyy + i * 8];
}

// ---------------- y = Wa*M + (Wb-Wa)*h + bias ----------------
__global__ __launch_bounds__(256) void k_gemm(const float* __restrict__ M, const float* __restrict__ h,
                                              const float* __restrict__ W, const float* __restrict__ bias,
                                              float* __restrict__ y) {
    __shared__ float Ws[64][33];
    __shared__ float Xs[32][65];
    int b = blockIdx.z;
    int o0 = blockIdx.y * 64;
    int n0 = blockIdx.x * 64;
    int tid = threadIdx.x;
    int tx = tid & 15, ty = tid >> 4;
    float acc[4][4] = {};
    const float* Mb = M + (size_t)b * NN * CC;
    const float* hb = h + (size_t)b * CC * NN;

    for (int c0 = 0; c0 < CC; c0 += 32) {
        for (int i = tid; i < 64 * 32; i += 256) {
            int c = i & 31, o = i >> 5;
            Ws[o][c] = W[(size_t)(o0 + o) * TWO_CC + c0 + c];
        }
        for (int i = tid; i < 64 * 32; i += 256) {
            int c = i & 31, nn = i >> 5;
            Xs[c][nn] = Mb[(size_t)(n0 + nn) * CC + c0 + c];
        }
        __syncthreads();
        for (int c = 0; c < 32; ++c) {
            float a[4], bb[4];
#pragma unroll
            for (int q = 0; q < 4; ++q) { a[q] = Ws[ty * 4 + q][c]; bb[q] = Xs[c][tx * 4 + q]; }
#pragma unroll
            for (int i2 = 0; i2 < 4; ++i2)
#pragma unroll
                for (int j = 0; j < 4; ++j) acc[i2][j] += a[i2] * bb[j];
        }
        __syncthreads();
    }
    for (int c0 = 0; c0 < CC; c0 += 32) {
        for (int i = tid; i < 64 * 32; i += 256) {
            int c = i & 31, o = i >> 5;
            const float* wr = W + (size_t)(o0 + o) * TWO_CC;
            Ws[o][c] = wr[CC + c0 + c] - wr[c0 + c];
        }
        for (int i = tid; i < 64 * 32; i += 256) {
            int nn = i & 63, c = i >> 6;
            Xs[c][nn] = hb[(size_t)(c0 + c) * NN + n0 + nn];
        }
        __syncthreads();
        for (int c = 0; c < 32; ++c) {
            float a[4], bb[4];
#pragma unroll
            for (int q = 0; q < 4; ++q) { a[q] = Ws[ty * 4 + q][c]; bb[q] = Xs[c][tx * 4 + q]; }
#pragma unroll
            for (int i2 = 0; i2 < 4; ++i2)
#pragma unroll
                for (int j = 0; j < 4; ++j) acc[i2][j] += a[i2] * bb[j];
        }
        __syncthreads();
    }
#pragma unroll
    for (int i2 = 0; i2 < 4; ++i2) {
        int o = o0 + ty * 4 + i2;
        float bv = bias[o];
#pragma unroll
        for (int j = 0; j < 4; ++j)
            y[((size_t)b * CC + o) * NN + n0 + tx * 4 + j] = acc[i2][j] + bv;
    }
}

// ---------------- per-(b,o) mean/var(ddof=1), relu, optional residual ----------------
__global__ __launch_bounds__(256) void k_norm(const float* __restrict__ y, const float* __restrict__ res,
                                              float* __restrict__ out, int add_res) {
    int bo = blockIdx.x;
    const float* row = y + (size_t)bo * NN;
    float s = 0.f, s2 = 0.f;
    for (int n = threadIdx.x; n < NN; n += 256) {
        float v = row[n];
        s += v;
        s2 += v * v;
    }
#pragma unroll
    for (int off = 32; off > 0; off >>= 1) {
        s += __shfl_down(s, off, 64);
        s2 += __shfl_down(s2, off, 64);
    }
    __shared__ float ss[4], ss2[4];
    int wave = threadIdx.x >> 6, lane = threadIdx.x & 63;
    if (lane == 0) { ss[wave] = s; ss2[wave] = s2; }
    __syncthreads();
    if (threadIdx.x == 0) {
        float S = ss[0] + ss[1] + ss[2] + ss[3];
        float S2 = ss2[0] + ss2[1] + ss2[2] + ss2[3];
        float mean = S * (1.f / NN);
        float var = (S2 - S * mean) * (1.f / (NN - 1));
        ss[0] = mean;
        ss2[0] = rsqrtf(var + 1e-3f);
    }
    __syncthreads();
    float mean = ss[0], inv = ss2[0];
    for (int n = threadIdx.x; n < NN; n += 256) {
        float v = (row[n] - mean) * inv;
        v = fmaxf(v, 0.f);
        if (add_res) v += res[(size_t)bo * NN + n];
        out[(size_t)bo * NN + n] = v;
    }
}

extern "C" void kernel_launch(void* const* d_in, const int* in_sizes, int n_in,
                              void* d_out, int out_size, void* d_ws, size_t ws_size,
                              hipStream_t stream) {
    const float* x  = (const float*)d_in[0];
    const float* W1 = (const float*)d_in[1];
    const float* b1 = (const float*)d_in[2];
    const float* W2 = (const float*)d_in[3];
    const float* b2 = (const float*)d_in[4];
    float* out = (float*)d_out;

    char* wsb = (char*)d_ws;
    double* xx = (double*)wsb;                          // 8*2048 f64 = 131072 B
    char* p = wsb + (size_t)BB * NN * 8;
    float* ht = (float*)p;    p += (size_t)BB * NN * CC * 4;    // 8 MB
    float* M  = (float*)p;    p += (size_t)BB * NN * CC * 4;    // 8 MB
    float* y  = (float*)p;    p += (size_t)BB * CC * NN * 4;    // 8 MB
    float* h1 = (float*)p;                                      // 8 MB

    // screened candidate lists (12 per row per my-quarter) live in y's region —
    // y is dead until k_gemm, and cand is consumed by k_rg before that.
    int* cand = (int*)y;                                        // 8*4*2048*12*4 = 3.1 MB

    auto layer = [&](const float* hin, const float* Wt, const float* bt, float* hout, int add_res) {
        hipLaunchKernelGGL(k_xx, dim3((BB * NN) / 256), dim3(256), 0, stream, hin, xx);
        hipLaunchKernelGGL(k_tr, dim3(NN / 32, CC / 32, BB), dim3(256), 0, stream, hin, ht);
        hipLaunchKernelGGL(k_knn, dim3(NN / 64, MYS, BB), dim3(256), 0, stream, hin, xx, cand);
        hipLaunchKernelGGL(k_rg, dim3(BB * NN), dim3(64), 0, stream, ht, xx, cand, M);
        hipLaunchKernelGGL(k_gemm, dim3(NN / 64, CC / 64, BB), dim3(256), 0, stream, M, hin, Wt, bt, y);
        hipLaunchKernelGGL(k_norm, dim3(BB * CC), dim3(256), 0, stream, y, x, hout, add_res);
    };

    layer(x, W1, b1, h1, 0);
    layer(h1, W2, b2, out, 1);
}